// Round 23
// baseline (222.071 us; speedup 1.0000x reference)
//
#include <hip/hip_runtime.h>
#include <cstdint>

#define K_NE 16
constexpr int B = 8, N = 2048, F = 128;
constexpr size_t NSEND = (size_t)B * N;                 // 16384 sender rows
constexpr size_t EDGE_FLOATS = NSEND * K_NE * 256;      // 67,108,864
constexpr int SPB = 16;                                 // senders per block

typedef _Float16 half8 __attribute__((ext_vector_type(8)));
typedef float floatx4 __attribute__((ext_vector_type(4)));

#define SCALE 2048.0f                    // exact power of 2
#define INV_SC2 2.384185791015625e-07f   // 2^-22, exact
#define F16_MIN_NORM 6.103515625e-05f    // 2^-14

// ---------------- K0: row norms (one wave per 128-float row) ----------------
__global__ __launch_bounds__(256) void norms_kernel(const float* __restrict__ X,
                                                    float* __restrict__ out) {
    int tid = blockIdx.x * 256 + threadIdx.x;
    int w = tid >> 6, lane = tid & 63;
    const float2 v = ((const float2*)(X + (size_t)w * F))[lane];
    float s = v.x * v.x + v.y * v.y;
    #pragma unroll
    for (int off = 32; off; off >>= 1) s += __shfl_xor(s, off);
    if (lane == 0) out[w] = s;
}

__device__ __forceinline__ void cvt_hilo(float a, _Float16& h, _Float16& l) {
    a *= SCALE;
    h = (_Float16)a;
    if (fabsf((float)h) < F16_MIN_NORM) h = (_Float16)0.0f;
    l = (_Float16)(a - (float)h);
    if (fabsf((float)l) < F16_MIN_NORM) l = (_Float16)0.0f;
}

#define KEYC(U, C) ((C) == 0 ? (U).x : (C) == 1 ? (U).y : (C) == 2 ? (U).z : (U).w)

// ---- K1: FUSED score + top-16 + connectivity + edges -----------------------
// Block = 16 waves x 64 = 1024 threads, owns 16 senders x all 2048 receivers.
// Phase 1: wave wv computes cols [wv*128, wv*128+128) via mfma_16x16x32_f16
// with on-the-fly f32 -> scaled hi/lo conversion (identical math + MFMA chain
// order to r18 -> bit-identical scores); keys to 128 KB LDS.
// Phase 2: wave wv selects row wv's top-16 (r18 exact path) and writes the
// conn row + 16 edge rows. No score round-trip through HBM.
__global__ __launch_bounds__(1024) void fused_kernel(const float* __restrict__ S,
                                                     const float* __restrict__ Rv,
                                                     const float* __restrict__ x2,
                                                     const float* __restrict__ y2,
                                                     float* __restrict__ conn,
                                                     float* __restrict__ edges_out) {
    __shared__ uint32_t keys[SPB][N];     // 128 KB
    __shared__ double candbuf[16][64];    // 8 KB
    const int t = threadIdx.x, lane = t & 63, wv = t >> 6;   // wv 0..15
    const int blk = blockIdx.x;           // 0..1023
    const int bz = blk >> 7;              // batch
    const int sg0 = (blk & 127) * SPB;    // batch-local sender base
    const int lr = lane & 15, kgrp = lane >> 4;
    const double MAGIC = 4503599627370496.0;   // 2^52

    const float* x2b = x2 + bz * N;
    const float* y2b = y2 + bz * N;
    const float* rbase = Rv + (size_t)bz * N * F;

    // ---- A fragments: 16 senders x K=128, f32 -> hi/lo in regs ------------
    half8 ah[4], al[4];
    {
        const float* arow = S + ((size_t)(bz * N + sg0) + lr) * F;
        #pragma unroll
        for (int ks = 0; ks < 4; ++ks) {
            const int k0 = ks * 32 + kgrp * 8;
            const float4 f0 = *(const float4*)(arow + k0);
            const float4 f1 = *(const float4*)(arow + k0 + 4);
            const float av[8] = {f0.x, f0.y, f0.z, f0.w, f1.x, f1.y, f1.z, f1.w};
            #pragma unroll
            for (int j = 0; j < 8; ++j) {
                _Float16 hh, ll;
                cvt_hilo(av[j], hh, ll);
                ah[ks][j] = hh;
                al[ks][j] = ll;
            }
        }
    }
    float xr[4];
    #pragma unroll
    for (int r = 0; r < 4; ++r) xr[r] = x2b[sg0 + kgrp * 4 + r];

    // ---- phase 1: 8 col-tiles of 16 per wave ------------------------------
    #pragma unroll 1
    for (int ct = 0; ct < 8; ++ct) {
        const int col0 = wv * 128 + ct * 16;
        const float* brow = rbase + (size_t)(col0 + lr) * F;
        floatx4 acc = {0.f, 0.f, 0.f, 0.f};
        #pragma unroll
        for (int ks = 0; ks < 4; ++ks) {
            const int k0 = ks * 32 + kgrp * 8;
            const float4 f0 = *(const float4*)(brow + k0);
            const float4 f1 = *(const float4*)(brow + k0 + 4);
            const float bv[8] = {f0.x, f0.y, f0.z, f0.w, f1.x, f1.y, f1.z, f1.w};
            half8 bh, bl;
            #pragma unroll
            for (int j = 0; j < 8; ++j) {
                _Float16 hh, ll;
                cvt_hilo(bv[j], hh, ll);
                bh[j] = hh;
                bl[j] = ll;
            }
            acc = __builtin_amdgcn_mfma_f32_16x16x32_f16(ah[ks], bh, acc, 0, 0, 0);
            acc = __builtin_amdgcn_mfma_f32_16x16x32_f16(ah[ks], bl, acc, 0, 0, 0);
            acc = __builtin_amdgcn_mfma_f32_16x16x32_f16(al[ks], bh, acc, 0, 0, 0);
        }
        const float yv = y2b[col0 + lr];
        #pragma unroll
        for (int r = 0; r < 4; ++r) {
            const float d = acc[r] * INV_SC2;   // exact unscale
            const float sc = fabsf((-2.0f * d + xr[r]) + yv);
            keys[kgrp * 4 + r][col0 + lr] = __float_as_uint(sc);
        }
    }
    __syncthreads();

    // ---- phase 2: wave wv -> row wv (r18 exact select) --------------------
    const int g = bz * N + sg0 + wv;      // global sender id
    double* cbuf = candbuf[wv];
    const uint4* krow = (const uint4*)keys[wv];

    uint4 u[8];
    uint32_t mk = 0xFFFFFFFFu;
    #pragma unroll
    for (int jj = 0; jj < 8; ++jj) {
        u[jj] = krow[jj * 64 + lane];
        mk = mk < u[jj].x ? mk : u[jj].x;
        mk = mk < u[jj].y ? mk : u[jj].y;
        mk = mk < u[jj].z ? mk : u[jj].z;
        mk = mk < u[jj].w ? mk : u[jj].w;
    }

    uint32_t v = mk;
    #pragma unroll
    for (int k = 2; k <= 64; k <<= 1) {
        #pragma unroll
        for (int j = k >> 1; j >= 1; j >>= 1) {
            uint32_t o = (uint32_t)__shfl_xor((int)v, j);
            const bool take_min = (((lane & j) == 0) == ((lane & k) == 0));
            const uint32_t mn = v < o ? v : o;
            const uint32_t mx = v < o ? o : v;
            v = take_min ? mn : mx;
        }
    }
    const uint32_t T16 = (uint32_t)__shfl((int)v, 15);

    int myc = 0;
    #pragma unroll
    for (int jj = 0; jj < 8; ++jj)
        #pragma unroll
        for (int c = 0; c < 4; ++c)
            myc += (KEYC(u[jj], c) <= T16) ? 1 : 0;
    int off = myc;
    #pragma unroll
    for (int d = 1; d < 64; d <<= 1) {
        const int o = __shfl_up(off, d);
        if (lane >= d) off += o;
    }
    const int total = __shfl(off, 63);
    const int base = off - myc;

    int ixs[16];
    if (total <= 64) {
        int p = base;
        #pragma unroll
        for (int jj = 0; jj < 8; ++jj)
            #pragma unroll
            for (int c = 0; c < 4; ++c) {
                const uint32_t key = KEYC(u[jj], c);
                if (key <= T16) {
                    cbuf[p] = (double)key * 2048.0 + (double)(jj * 256 + lane * 4 + c);
                    ++p;
                }
            }
        double d = (lane < total) ? cbuf[lane] : 1e300;
        #pragma unroll
        for (int k = 2; k <= 64; k <<= 1) {
            #pragma unroll
            for (int j = k >> 1; j >= 1; j >>= 1) {
                const double o = __shfl_xor(d, j);
                const bool take_min = (((lane & j) == 0) == ((lane & k) == 0));
                d = take_min ? fmin(d, o) : fmax(d, o);
            }
        }
        const int myidx = (int)(__double_as_longlong(d + MAGIC) & 2047);
        #pragma unroll
        for (int e = 0; e < 16; ++e) ixs[e] = __shfl(myidx, e);
    } else {
        // ---- fallback (tie storm): register-masked iterative extraction --
        uint32_t fk = 0xFFFFFFFFu, fi = 0;
        #pragma unroll
        for (int jj = 0; jj < 8; ++jj) {
            const uint32_t bse = (uint32_t)(jj * 256 + lane * 4);
            if (u[jj].x < fk) { fk = u[jj].x; fi = bse; }
            if (u[jj].y < fk) { fk = u[jj].y; fi = bse + 1; }
            if (u[jj].z < fk) { fk = u[jj].z; fi = bse + 2; }
            if (u[jj].w < fk) { fk = u[jj].w; fi = bse + 3; }
        }
        #pragma unroll
        for (int it = 0; it < 16; ++it) {
            const uint32_t ck = fk, ci = fi;
            uint32_t gk = fk, gi = fi;
            #pragma unroll
            for (int o2 = 32; o2; o2 >>= 1) {
                uint32_t ok = (uint32_t)__shfl_xor((int)gk, o2);
                uint32_t oi = (uint32_t)__shfl_xor((int)gi, o2);
                if (ok < gk || (ok == gk && oi < gi)) { gk = ok; gi = oi; }
            }
            ixs[it] = (int)gi;
            if (ck == gk && ci == gi) {
                const int djj = (int)(gi >> 8), dc = (int)(gi & 3);
                #pragma unroll
                for (int jj = 0; jj < 8; ++jj)
                    if (jj == djj) {
                        if (dc == 0) u[jj].x = 0xFFFFFFFFu;
                        else if (dc == 1) u[jj].y = 0xFFFFFFFFu;
                        else if (dc == 2) u[jj].z = 0xFFFFFFFFu;
                        else u[jj].w = 0xFFFFFFFFu;
                    }
                fk = 0xFFFFFFFFu; fi = 0;
                #pragma unroll
                for (int jj = 0; jj < 8; ++jj) {
                    const uint32_t bse = (uint32_t)(jj * 256 + lane * 4);
                    if (u[jj].x < fk) { fk = u[jj].x; fi = bse; }
                    if (u[jj].y < fk) { fk = u[jj].y; fi = bse + 1; }
                    if (u[jj].z < fk) { fk = u[jj].z; fi = bse + 2; }
                    if (u[jj].w < fk) { fk = u[jj].w; fi = bse + 3; }
                }
            }
        }
    }

    // ---- ranks: output slot = ascending receiver-index position -----------
    int rank[16];
    #pragma unroll
    for (int e = 0; e < 16; ++e) {
        int r = 0;
        #pragma unroll
        for (int f = 0; f < 16; ++f) r += (ixs[f] < ixs[e]) ? 1 : 0;
        rank[e] = r;
    }

    // ---- connectivity row --------------------------------------------------
    uint32_t mask = 0;
    #pragma unroll
    for (int e = 0; e < 16; ++e) {
        const int ix = ixs[e];
        const int lane_t = (ix >> 2) & 63;
        const int bitpos = ((ix >> 8) << 2) | (ix & 3);
        if (lane == lane_t) mask |= (1u << bitpos);
    }
    float* crow = conn + (size_t)g * N;
    #pragma unroll
    for (int j = 0; j < 8; ++j) {
        float4 vv;
        vv.x = (mask >> (j * 4 + 0)) & 1u ? 1.f : 0.f;
        vv.y = (mask >> (j * 4 + 1)) & 1u ? 1.f : 0.f;
        vv.z = (mask >> (j * 4 + 2)) & 1u ? 1.f : 0.f;
        vv.w = (mask >> (j * 4 + 3)) & 1u ? 1.f : 0.f;
        *(float4*)(crow + j * 256 + lane * 4) = vv;
    }

    // ---- edge rows: [sender_feat(128) | recv_feat(128)] -------------------
    const float* srow = S + (size_t)g * F;
    float4 vs = {0.f, 0.f, 0.f, 0.f};
    if (lane < 32) vs = *(const float4*)(srow + lane * 4);
    #pragma unroll
    for (int e = 0; e < 16; ++e) {
        float4 vv = vs;
        if (lane >= 32)
            vv = *(const float4*)(rbase + (size_t)ixs[e] * F + (lane - 32) * 4);
        *(float4*)(edges_out + ((size_t)g * K_NE + rank[e]) * 256 + lane * 4) = vv;
    }
}

extern "C" void kernel_launch(void* const* d_in, const int* in_sizes, int n_in,
                              void* d_out, int out_size, void* d_ws, size_t ws_size,
                              hipStream_t stream) {
    (void)in_sizes; (void)n_in; (void)out_size; (void)ws_size;
    const float* recv = (const float*)d_in[0];
    const float* send = (const float*)d_in[1];
    float* out = (float*)d_out;
    float* conn = out + EDGE_FLOATS;
    float* x2 = (float*)((char*)d_ws + (262144u * 4));
    float* y2 = x2 + NSEND;

    norms_kernel<<<4096, 256, 0, stream>>>(send, x2);
    norms_kernel<<<4096, 256, 0, stream>>>(recv, y2);
    fused_kernel<<<1024, 1024, 0, stream>>>(send, recv, x2, y2, conn, out);
}